// Round 3
// baseline (444.901 us; speedup 1.0000x reference)
//
#include <hip/hip_runtime.h>

#define N_NODES 4096
#define F_IN 512
#define NHID 256
#define HD 1024        // 4 heads * 256
#define NPAD 1152      // padded N for adjacency GEMM (9 * 128)

typedef _Float16 half8 __attribute__((ext_vector_type(8)));
typedef _Float16 half4 __attribute__((ext_vector_type(4)));
typedef float floatx4 __attribute__((ext_vector_type(4)));
typedef float float4v __attribute__((ext_vector_type(4)));
typedef unsigned short ushort4v __attribute__((ext_vector_type(4)));
typedef int int4v __attribute__((ext_vector_type(4)));
typedef unsigned int uint4v __attribute__((ext_vector_type(4)));

__device__ __forceinline__ float bf2f(unsigned short u) {
  union { unsigned int i; float f; } x; x.i = ((unsigned int)u) << 16; return x.f;
}
// order-preserving float<->uint encode for atomicMax over signed floats
__device__ __forceinline__ unsigned int encf(float f) {
  union { float f; unsigned int u; } x; x.f = f;
  return (x.u & 0x80000000u) ? ~x.u : (x.u | 0x80000000u);
}
__device__ __forceinline__ float decf(unsigned int u) {
  union { unsigned int u; float f; } x;
  x.u = (u & 0x80000000u) ? (u & 0x7FFFFFFFu) : ~u;
  return x.f;
}

__device__ __forceinline__ void async_copy16(const void* g, void* l) {
  __builtin_amdgcn_global_load_lds((const __attribute__((address_space(1))) void*)g,
                                   (__attribute__((address_space(3))) void*)l, 16, 0, 0);
}

// ---------------- representation detector: 1 = bf16 halfwords, 0 = fp32 words ----------------
__global__ void detect_kernel(const unsigned short* __restrict__ hbits, int* __restrict__ flag) {
  const int t = threadIdx.x;
  int cnt = 0;
  for (int i = t; i < 1024; i += 256) {
    int e = (hbits[i] >> 7) & 0xFF;
    cnt += (e >= 115 && e <= 135) ? 1 : 0;
  }
  __shared__ int red[256];
  red[t] = cnt; __syncthreads();
  for (int s = 128; s > 0; s >>= 1) { if (t < s) red[t] += red[t + s]; __syncthreads(); }
  if (t == 0) flag[0] = (red[0] >= 900) ? 1 : 0;
}

// ---------------- GEMM: C[M x ldc] = A[M x K] * BT[N x K]^T, fp32 accum ----------------
// 128x128 tile, BK=32, 256 threads (4 waves, each 64x64 via 4x4 mfma_f32_16x16x32_f16)
template <typename OutT>
__global__ __launch_bounds__(256) void gemm_bt(
    const _Float16* __restrict__ A, const _Float16* __restrict__ BT,
    OutT* __restrict__ C, int K, int ldc)
{
  __shared__ _Float16 sA[128 * 32];
  __shared__ _Float16 sB[128 * 32];
  const int n0 = blockIdx.x * 128;
  const int m0 = blockIdx.y * 128;
  const int t = threadIdx.x;
  const int w = t >> 6;
  const int lane = t & 63;
  const int wm = (w >> 1) << 6;
  const int wn = (w & 1) << 6;

  floatx4 acc[4][4] = {};

  const int l4 = lane >> 2;         // 0..15 (row within 16-row chunk)
  const int kk = (lane & 3) << 3;   // k element offset 0,8,16,24
  const int c0 = w << 1;            // this wave stages chunks c0, c0+1

  const _Float16* gA = A + (long)m0 * K;
  const _Float16* gBT = BT + (long)n0 * K;

  const int koff = (lane >> 4) << 3;   // quad*8
  const int rA = wm + (lane & 15);
  const int rB = wn + (lane & 15);

  for (int k0 = 0; k0 < K; k0 += 32) {
    __syncthreads();   // previous compute done; safe to overwrite LDS
#pragma unroll
    for (int p = 0; p < 2; ++p) {
      const int c = c0 + p;
      const int row = c * 16 + l4;
      async_copy16(gA + (long)row * K + k0 + kk, &sA[c * 512 + lane * 8]);
      async_copy16(gBT + (long)row * K + k0 + kk, &sB[c * 512 + lane * 8]);
    }
    __syncthreads();   // drains vmcnt -> LDS tiles visible
    half8 af[4], bf[4];
#pragma unroll
    for (int i = 0; i < 4; ++i)
      af[i] = *(const half8*)&sA[(rA + i * 16) * 32 + koff];
#pragma unroll
    for (int i = 0; i < 4; ++i)
      bf[i] = *(const half8*)&sB[(rB + i * 16) * 32 + koff];
#pragma unroll
    for (int i = 0; i < 4; ++i)
#pragma unroll
      for (int j = 0; j < 4; ++j)
        acc[i][j] = __builtin_amdgcn_mfma_f32_16x16x32_f16(af[i], bf[j], acc[i][j], 0, 0, 0);
  }

  const int q4 = (lane >> 4) << 2;
#pragma unroll
  for (int i = 0; i < 4; ++i) {
#pragma unroll
    for (int j = 0; j < 4; ++j) {
      const int gr = m0 + wm + i * 16 + q4;
      const int gc = n0 + wn + j * 16 + (lane & 15);
#pragma unroll
      for (int r = 0; r < 4; ++r)
        C[(long)(gr + r) * ldc + gc] = (OutT)acc[i][j][r];
    }
  }
}

// ---------------- h (bf16 OR fp32 per flag) -> f16 ----------------
__global__ void cvt_h_kernel(const void* __restrict__ in, _Float16* __restrict__ out,
                             const int* __restrict__ flag, int n8) {
  int i = blockIdx.x * 256 + threadIdx.x;
  if (i >= n8) return;
  half8 o;
  if (*flag) {
    union { uint4v v; unsigned short s[8]; } u;
    u.v = ((const uint4v*)in)[i];
#pragma unroll
    for (int e = 0; e < 8; ++e) o[e] = (_Float16)bf2f(u.s[e]);
  } else {
    const float4v* f = (const float4v*)in + 2 * i;
    float4v x0 = f[0], x1 = f[1];
#pragma unroll
    for (int e = 0; e < 4; ++e) { o[e] = (_Float16)x0[e]; o[4 + e] = (_Float16)x1[e]; }
  }
  ((half8*)out)[i] = o;
}

// ---------------- adjacency int32 (0/1) -> f16 ----------------
__global__ void cvt_adj_kernel(const int* __restrict__ adj, _Float16* __restrict__ out, int n8) {
  int i = blockIdx.x * 256 + threadIdx.x;
  if (i >= n8) return;
  int4v A = ((const int4v*)adj)[2 * i];
  int4v B = ((const int4v*)adj)[2 * i + 1];
  half8 o;
#pragma unroll
  for (int e = 0; e < 4; ++e) {
    o[e]     = (_Float16)(A[e] > 0 ? 1.0f : 0.0f);
    o[4 + e] = (_Float16)(B[e] > 0 ? 1.0f : 0.0f);
  }
  ((half8*)out)[i] = o;
}

// ---------------- a (bf16 OR fp32) -> fp32, 2048 elements, 1 block ----------------
__global__ void cvt_a_kernel(const void* __restrict__ a, float* __restrict__ aF,
                             const int* __restrict__ flag) {
  const int t = threadIdx.x;
  const int bf = *flag;
#pragma unroll
  for (int e = 0; e < 8; ++e) {
    int idx = t * 8 + e;
    aF[idx] = bf ? bf2f(((const unsigned short*)a)[idx]) : ((const float*)a)[idx];
  }
}

// ---------------- W [512 x 1024] (bf16 OR fp32) -> WT [1024 x 512] f16 ----------------
__global__ void transpose_w_kernel(const void* __restrict__ W, _Float16* __restrict__ WT,
                                   const int* __restrict__ flag) {
  __shared__ _Float16 tile[64][72];
  const int k0 = blockIdx.x * 64, n0 = blockIdx.y * 64;
  const int t = threadIdx.x, r = t >> 3, c = t & 7;
  const int bf = *flag;
#pragma unroll
  for (int q = 0; q < 2; ++q) {
    int k = r + q * 32;
    half8 v;
    if (bf) {
      union { uint4v vv; unsigned short s[8]; } u;
      u.vv = *(const uint4v*)&((const unsigned short*)W)[(long)(k0 + k) * HD + n0 + c * 8];
#pragma unroll
      for (int e = 0; e < 8; ++e) v[e] = (_Float16)bf2f(u.s[e]);
    } else {
      const float4v* f = (const float4v*)&((const float*)W)[(long)(k0 + k) * HD + n0 + c * 8];
      float4v x0 = f[0], x1 = f[1];
#pragma unroll
      for (int e = 0; e < 4; ++e) { v[e] = (_Float16)x0[e]; v[4 + e] = (_Float16)x1[e]; }
    }
    *(half8*)&tile[k][c * 8] = v;
  }
  __syncthreads();
#pragma unroll
  for (int q = 0; q < 2; ++q) {
    int n = r + q * 32;
    half8 o;
#pragma unroll
    for (int e = 0; e < 8; ++e) o[e] = tile[c * 8 + e][n];
    *(half8*)&WT[(long)(n0 + n) * F_IN + k0 + c * 8] = o;
  }
}

// ---------------- tgt[h,i] = sum_d leaky_relu(ht[i, h*256+d]) * aF[h, 256+d]; per-head max ----------------
__global__ void tgt_kernel(const _Float16* __restrict__ ht, const float* __restrict__ aF,
                           float* __restrict__ tgt, unsigned int* __restrict__ mEnc) {
  const int i = blockIdx.x;
  const int t = threadIdx.x, h = t >> 6, lane = t & 63;
  half4 v = *(const half4*)&ht[(long)i * HD + h * NHID + lane * 4];
  float4v av = *(const float4v*)&aF[h * 512 + NHID + lane * 4];
  float s = 0.f;
#pragma unroll
  for (int e = 0; e < 4; ++e) {
    float x = (float)v[e];
    x = x > 0.f ? x : 0.1f * x;
    s += x * av[e];
  }
#pragma unroll
  for (int o = 32; o > 0; o >>= 1) s += __shfl_down(s, o);
  if (lane == 0) {
    tgt[h * N_NODES + i] = s;
    atomicMax(&mEnc[h], encf(s));
  }
}

// ---------------- w = exp(tgt - m); write fp32 wbuf + VT rows 1024..1027 ----------------
__global__ void wexp_kernel(const float* __restrict__ tgt, const unsigned int* __restrict__ mEnc,
                            float* __restrict__ wbuf, _Float16* __restrict__ VT) {
  const int h = blockIdx.y;
  const int j = blockIdx.x * 256 + threadIdx.x;
  const float m = decf(mEnc[h]);
  const float w = __expf(tgt[h * N_NODES + j] - m);
  wbuf[h * N_NODES + j] = w;
  VT[(long)(HD + h) * N_NODES + j] = (_Float16)w;
}

// ---------------- VT[n, j] = w[n>>8, j] * ht[j, n]  (scaled transpose, 64x64 LDS tiles) ----------------
__global__ void scaled_transpose_kernel(const _Float16* __restrict__ ht, const float* __restrict__ wbuf,
                                        _Float16* __restrict__ VT) {
  __shared__ _Float16 tile[64][72];
  const int j0 = blockIdx.x * 64, n0 = blockIdx.y * 64;
  const int t = threadIdx.x, r = t >> 3, c = t & 7;
#pragma unroll
  for (int q = 0; q < 2; ++q) {
    int j = r + q * 32;
    *(half8*)&tile[j][c * 8] = *(const half8*)&ht[(long)(j0 + j) * HD + n0 + c * 8];
  }
  __syncthreads();
  const int h = n0 >> 8;
  const float* wrow = wbuf + h * N_NODES + j0;
#pragma unroll
  for (int q = 0; q < 2; ++q) {
    int n = r + q * 32;
    half8 o;
#pragma unroll
    for (int e = 0; e < 8; ++e) {
      int j = c * 8 + e;
      o[e] = (_Float16)(wrow[j] * (float)tile[j][n]);
    }
    *(half8*)&VT[(long)(n0 + n) * N_NODES + j0 + c * 8] = o;
  }
}

// ---------------- out[i,d] = fp32( 0.25 * sum_h S[i, h*256+d] / S[i, 1024+h] ) ----------------
__global__ void epilogue_kernel(const float* __restrict__ S, float* __restrict__ out) {
  const int i = blockIdx.x, d = threadIdx.x;
  const float* row = S + (long)i * NPAD;
  float r = 0.f;
#pragma unroll
  for (int h = 0; h < 4; ++h) r += row[h * NHID + d] / row[HD + h];
  out[(long)i * NHID + d] = 0.25f * r;
}

extern "C" void kernel_launch(void* const* d_in, const int* in_sizes, int n_in,
                              void* d_out, int out_size, void* d_ws, size_t ws_size,
                              hipStream_t stream) {
  // map inputs by element count (robust to ordering): h=2097152, adj=16777216, W=524288, a=2048
  const void* h = nullptr; const int* adj = nullptr; const void* W = nullptr; const void* a = nullptr;
  for (int i = 0; i < n_in; ++i) {
    switch (in_sizes[i]) {
      case 2097152:  h   = d_in[i]; break;
      case 16777216: adj = (const int*)d_in[i]; break;
      case 524288:   W   = d_in[i]; break;
      case 2048:     a   = d_in[i]; break;
      default: break;
    }
  }
  float* out = (float*)d_out;  // reference output dtype: float32 [4096,256]

  char* ws = (char*)d_ws;
  const size_t OFF_ADJF = 0;                       // 33,554,432  adj as f16
  const size_t OFF_VT   = 33554432;                //  9,437,184  VT [1152 x 4096] f16
  const size_t OFF_TGT  = OFF_VT + 9437184;        //     65,536  tgt fp32 [4 x 4096]
  const size_t OFF_WBUF = OFF_TGT + 65536;         //     65,536  w fp32 [4 x 4096]
  const size_t OFF_M    = OFF_WBUF + 65536;        //        256  encoded max (16B) + flag
  const size_t OFF_AF   = OFF_M + 256;             //      8,192  a as fp32
  const size_t OFF_X    = OFF_AF + 8192;           // overlap region
  const size_t NEED     = OFF_X + 18874368;        // S fp32 [4096 x 1152]
  if (ws_size < NEED || !h || !adj || !W || !a) return;

  _Float16* adjF = (_Float16*)(ws + OFF_ADJF);
  _Float16* VT   = (_Float16*)(ws + OFF_VT);
  float*    tgt  = (float*)(ws + OFF_TGT);
  float*    wbuf = (float*)(ws + OFF_WBUF);
  unsigned int* mEnc = (unsigned int*)(ws + OFF_M);
  int*      flag = (int*)(ws + OFF_M + 32);
  float*    aF   = (float*)(ws + OFF_AF);
  // region X: hF/WT/ht live until scaled_transpose; S (the adj-GEMM output) aliases them after
  _Float16* hF = (_Float16*)(ws + OFF_X);                  // 4,194,304
  _Float16* WT = (_Float16*)(ws + OFF_X + 4194304);        // 1,048,576
  _Float16* ht = (_Float16*)(ws + OFF_X + 5242880);        // 8,388,608
  float*    S  = (float*)(ws + OFF_X);                     // 18,874,368 (aliases dead hF/WT/ht)

  hipMemsetAsync(mEnc, 0, 16, stream);
  detect_kernel<<<1, 256, 0, stream>>>((const unsigned short*)h, flag);
  cvt_h_kernel<<<1024, 256, 0, stream>>>(h, hF, flag, 262144);
  cvt_adj_kernel<<<8192, 256, 0, stream>>>(adj, adjF, 2097152);
  cvt_a_kernel<<<1, 256, 0, stream>>>(a, aF, flag);
  transpose_w_kernel<<<dim3(8, 16), 256, 0, stream>>>(W, WT, flag);
  // ht[4096 x 1024] = h @ W
  gemm_bt<_Float16><<<dim3(8, 32), 256, 0, stream>>>(hF, WT, ht, F_IN, HD);
  tgt_kernel<<<4096, 256, 0, stream>>>(ht, aF, tgt, mEnc);
  wexp_kernel<<<dim3(16, 4), 256, 0, stream>>>(tgt, mEnc, wbuf, VT);
  scaled_transpose_kernel<<<dim3(64, 16), 256, 0, stream>>>(ht, wbuf, VT);
  // S[4096 x 1152] = adj @ [w*ht | w]
  gemm_bt<float><<<dim3(9, 32), 256, 0, stream>>>(adjF, VT, S, N_NODES, NPAD);
  epilogue_kernel<<<4096, 256, 0, stream>>>(S, out);
}

// Round 4
// 262.291 us; speedup vs baseline: 1.6962x; 1.6962x over previous
//
#include <hip/hip_runtime.h>

#define N_NODES 4096
#define F_IN 512
#define NHID 256
#define HD 1024        // 4 heads * 256
#define NPAD 1152      // padded N for adjacency GEMM (9 * 128)

typedef _Float16 half8 __attribute__((ext_vector_type(8)));
typedef _Float16 half4 __attribute__((ext_vector_type(4)));
typedef float floatx4 __attribute__((ext_vector_type(4)));
typedef float float4v __attribute__((ext_vector_type(4)));
typedef int int4v __attribute__((ext_vector_type(4)));
typedef unsigned int uint4v __attribute__((ext_vector_type(4)));

__device__ __forceinline__ float bf2f(unsigned short u) {
  union { unsigned int i; float f; } x; x.i = ((unsigned int)u) << 16; return x.f;
}

__device__ __forceinline__ void async_copy16(const void* g, void* l) {
  __builtin_amdgcn_global_load_lds((const __attribute__((address_space(1))) void*)g,
                                   (__attribute__((address_space(3))) void*)l, 16, 0, 0);
}

// ---------------- representation detector: 1 = bf16 halfwords, 0 = fp32 words ----------------
__global__ void detect_kernel(const unsigned short* __restrict__ hbits, int* __restrict__ flag) {
  const int t = threadIdx.x;
  int cnt = 0;
  for (int i = t; i < 1024; i += 256) {
    int e = (hbits[i] >> 7) & 0xFF;
    cnt += (e >= 115 && e <= 135) ? 1 : 0;
  }
  __shared__ int red[256];
  red[t] = cnt; __syncthreads();
  for (int s = 128; s > 0; s >>= 1) { if (t < s) red[t] += red[t + s]; __syncthreads(); }
  if (t == 0) flag[0] = (red[0] >= 900) ? 1 : 0;
}

// ---------------- GEMM: C[M x ldc] = A[M x K] * BT[N x K]^T, fp32 accum ----------------
// 128x128 tile, BK=32, 256 threads (4 waves, each 64x64 via 4x4 mfma_f32_16x16x32_f16)
template <typename OutT>
__global__ __launch_bounds__(256) void gemm_bt(
    const _Float16* __restrict__ A, const _Float16* __restrict__ BT,
    OutT* __restrict__ C, int K, int ldc)
{
  __shared__ _Float16 sA[128 * 32];
  __shared__ _Float16 sB[128 * 32];
  const int n0 = blockIdx.x * 128;
  const int m0 = blockIdx.y * 128;
  const int t = threadIdx.x;
  const int w = t >> 6;
  const int lane = t & 63;
  const int wm = (w >> 1) << 6;
  const int wn = (w & 1) << 6;

  floatx4 acc[4][4] = {};

  const int l4 = lane >> 2;         // 0..15 (row within 16-row chunk)
  const int kk = (lane & 3) << 3;   // k element offset 0,8,16,24
  const int c0 = w << 1;            // this wave stages chunks c0, c0+1

  const _Float16* gA = A + (long)m0 * K;
  const _Float16* gBT = BT + (long)n0 * K;

  const int koff = (lane >> 4) << 3;   // quad*8
  const int rA = wm + (lane & 15);
  const int rB = wn + (lane & 15);

  for (int k0 = 0; k0 < K; k0 += 32) {
    __syncthreads();   // previous compute done; safe to overwrite LDS
#pragma unroll
    for (int p = 0; p < 2; ++p) {
      const int c = c0 + p;
      const int row = c * 16 + l4;
      async_copy16(gA + (long)row * K + k0 + kk, &sA[c * 512 + lane * 8]);
      async_copy16(gBT + (long)row * K + k0 + kk, &sB[c * 512 + lane * 8]);
    }
    __syncthreads();   // drains vmcnt -> LDS tiles visible
    half8 af[4], bf[4];
#pragma unroll
    for (int i = 0; i < 4; ++i)
      af[i] = *(const half8*)&sA[(rA + i * 16) * 32 + koff];
#pragma unroll
    for (int i = 0; i < 4; ++i)
      bf[i] = *(const half8*)&sB[(rB + i * 16) * 32 + koff];
#pragma unroll
    for (int i = 0; i < 4; ++i)
#pragma unroll
      for (int j = 0; j < 4; ++j)
        acc[i][j] = __builtin_amdgcn_mfma_f32_16x16x32_f16(af[i], bf[j], acc[i][j], 0, 0, 0);
  }

  const int q4 = (lane >> 4) << 2;
#pragma unroll
  for (int i = 0; i < 4; ++i) {
#pragma unroll
    for (int j = 0; j < 4; ++j) {
      const int gr = m0 + wm + i * 16 + q4;
      const int gc = n0 + wn + j * 16 + (lane & 15);
#pragma unroll
      for (int r = 0; r < 4; ++r)
        C[(long)(gr + r) * ldc + gc] = (OutT)acc[i][j][r];
    }
  }
}

// ---------------- h (bf16 OR fp32 per flag) -> f16 ----------------
__global__ void cvt_h_kernel(const void* __restrict__ in, _Float16* __restrict__ out,
                             const int* __restrict__ flag, int n8) {
  int i = blockIdx.x * 256 + threadIdx.x;
  if (i >= n8) return;
  half8 o;
  if (*flag) {
    union { uint4v v; unsigned short s[8]; } u;
    u.v = ((const uint4v*)in)[i];
#pragma unroll
    for (int e = 0; e < 8; ++e) o[e] = (_Float16)bf2f(u.s[e]);
  } else {
    const float4v* f = (const float4v*)in + 2 * i;
    float4v x0 = f[0], x1 = f[1];
#pragma unroll
    for (int e = 0; e < 4; ++e) { o[e] = (_Float16)x0[e]; o[4 + e] = (_Float16)x1[e]; }
  }
  ((half8*)out)[i] = o;
}

// ---------------- adjacency int32 (0/1) -> f16 ----------------
__global__ void cvt_adj_kernel(const int* __restrict__ adj, _Float16* __restrict__ out, int n8) {
  int i = blockIdx.x * 256 + threadIdx.x;
  if (i >= n8) return;
  int4v A = ((const int4v*)adj)[2 * i];
  int4v B = ((const int4v*)adj)[2 * i + 1];
  half8 o;
#pragma unroll
  for (int e = 0; e < 4; ++e) {
    o[e]     = (_Float16)(A[e] > 0 ? 1.0f : 0.0f);
    o[4 + e] = (_Float16)(B[e] > 0 ? 1.0f : 0.0f);
  }
  ((half8*)out)[i] = o;
}

// ---------------- a (bf16 OR fp32) -> fp32, 2048 elements, 1 block ----------------
__global__ void cvt_a_kernel(const void* __restrict__ a, float* __restrict__ aF,
                             const int* __restrict__ flag) {
  const int t = threadIdx.x;
  const int bf = *flag;
#pragma unroll
  for (int e = 0; e < 8; ++e) {
    int idx = t * 8 + e;
    aF[idx] = bf ? bf2f(((const unsigned short*)a)[idx]) : ((const float*)a)[idx];
  }
}

// ---------------- W [512 x 1024] (bf16 OR fp32) -> WT [1024 x 512] f16 ----------------
__global__ void transpose_w_kernel(const void* __restrict__ W, _Float16* __restrict__ WT,
                                   const int* __restrict__ flag) {
  __shared__ _Float16 tile[64][72];
  const int k0 = blockIdx.x * 64, n0 = blockIdx.y * 64;
  const int t = threadIdx.x, r = t >> 3, c = t & 7;
  const int bf = *flag;
#pragma unroll
  for (int q = 0; q < 2; ++q) {
    int k = r + q * 32;
    half8 v;
    if (bf) {
      union { uint4v vv; unsigned short s[8]; } u;
      u.vv = *(const uint4v*)&((const unsigned short*)W)[(long)(k0 + k) * HD + n0 + c * 8];
#pragma unroll
      for (int e = 0; e < 8; ++e) v[e] = (_Float16)bf2f(u.s[e]);
    } else {
      const float4v* f = (const float4v*)&((const float*)W)[(long)(k0 + k) * HD + n0 + c * 8];
      float4v x0 = f[0], x1 = f[1];
#pragma unroll
      for (int e = 0; e < 4; ++e) { v[e] = (_Float16)x0[e]; v[4 + e] = (_Float16)x1[e]; }
    }
    *(half8*)&tile[k][c * 8] = v;
  }
  __syncthreads();
#pragma unroll
  for (int q = 0; q < 2; ++q) {
    int n = r + q * 32;
    half8 o;
#pragma unroll
    for (int e = 0; e < 8; ++e) o[e] = tile[c * 8 + e][n];
    *(half8*)&WT[(long)(n0 + n) * F_IN + k0 + c * 8] = o;
  }
}

// ---------------- tgt[h,i] = sum_d leaky_relu(ht[i, h*256+d]) * aF[h, 256+d]  (no atomics) ----------------
__global__ void tgt_kernel(const _Float16* __restrict__ ht, const float* __restrict__ aF,
                           float* __restrict__ tgt) {
  const int i = blockIdx.x;
  const int t = threadIdx.x, h = t >> 6, lane = t & 63;
  half4 v = *(const half4*)&ht[(long)i * HD + h * NHID + lane * 4];
  float4v av = *(const float4v*)&aF[h * 512 + NHID + lane * 4];
  float s = 0.f;
#pragma unroll
  for (int e = 0; e < 4; ++e) {
    float x = (float)v[e];
    x = x > 0.f ? x : 0.1f * x;
    s += x * av[e];
  }
#pragma unroll
  for (int o = 32; o > 0; o >>= 1) s += __shfl_down(s, o);
  if (lane == 0) tgt[h * N_NODES + i] = s;
}

// ---------------- per-head max over tgt[h, 0..4095] -> mF[h]  (1 block per head) ----------------
__global__ void reduce_max_kernel(const float* __restrict__ tgt, float* __restrict__ mF) {
  const int h = blockIdx.x, t = threadIdx.x;
  const float* row = tgt + h * N_NODES;
  float m = -3.0e38f;
#pragma unroll
  for (int q = 0; q < 4; ++q) {
    float4v v = *(const float4v*)&row[(t + q * 256) * 4];
#pragma unroll
    for (int e = 0; e < 4; ++e) m = fmaxf(m, v[e]);
  }
#pragma unroll
  for (int o = 32; o > 0; o >>= 1) m = fmaxf(m, __shfl_down(m, o));
  __shared__ float red[4];
  if ((t & 63) == 0) red[t >> 6] = m;
  __syncthreads();
  if (t == 0) mF[h] = fmaxf(fmaxf(red[0], red[1]), fmaxf(red[2], red[3]));
}

// ---------------- w = exp(tgt - m); write fp32 wbuf + VT rows 1024..1027 ----------------
__global__ void wexp_kernel(const float* __restrict__ tgt, const float* __restrict__ mF,
                            float* __restrict__ wbuf, _Float16* __restrict__ VT) {
  const int h = blockIdx.y;
  const int j = blockIdx.x * 256 + threadIdx.x;
  const float m = mF[h];
  const float w = __expf(tgt[h * N_NODES + j] - m);
  wbuf[h * N_NODES + j] = w;
  VT[(long)(HD + h) * N_NODES + j] = (_Float16)w;
}

// ---------------- VT[n, j] = w[n>>8, j] * ht[j, n]  (scaled transpose, 64x64 LDS tiles) ----------------
__global__ void scaled_transpose_kernel(const _Float16* __restrict__ ht, const float* __restrict__ wbuf,
                                        _Float16* __restrict__ VT) {
  __shared__ _Float16 tile[64][72];
  const int j0 = blockIdx.x * 64, n0 = blockIdx.y * 64;
  const int t = threadIdx.x, r = t >> 3, c = t & 7;
#pragma unroll
  for (int q = 0; q < 2; ++q) {
    int j = r + q * 32;
    *(half8*)&tile[j][c * 8] = *(const half8*)&ht[(long)(j0 + j) * HD + n0 + c * 8];
  }
  __syncthreads();
  const int h = n0 >> 8;
  const float* wrow = wbuf + h * N_NODES + j0;
#pragma unroll
  for (int q = 0; q < 2; ++q) {
    int n = r + q * 32;
    half8 o;
#pragma unroll
    for (int e = 0; e < 8; ++e) {
      int j = c * 8 + e;
      o[e] = (_Float16)(wrow[j] * (float)tile[j][n]);
    }
    *(half8*)&VT[(long)(n0 + n) * N_NODES + j0 + c * 8] = o;
  }
}

// ---------------- out[i,d] = fp32( 0.25 * sum_h S[i, h*256+d] / S[i, 1024+h] ) ----------------
__global__ void epilogue_kernel(const float* __restrict__ S, float* __restrict__ out) {
  const int i = blockIdx.x, d = threadIdx.x;
  const float* row = S + (long)i * NPAD;
  float r = 0.f;
#pragma unroll
  for (int h = 0; h < 4; ++h) r += row[h * NHID + d] / row[HD + h];
  out[(long)i * NHID + d] = 0.25f * r;
}

extern "C" void kernel_launch(void* const* d_in, const int* in_sizes, int n_in,
                              void* d_out, int out_size, void* d_ws, size_t ws_size,
                              hipStream_t stream) {
  // map inputs by element count: h=2097152, adj=16777216, W=524288, a=2048
  const void* h = nullptr; const int* adj = nullptr; const void* W = nullptr; const void* a = nullptr;
  for (int i = 0; i < n_in; ++i) {
    switch (in_sizes[i]) {
      case 2097152:  h   = d_in[i]; break;
      case 16777216: adj = (const int*)d_in[i]; break;
      case 524288:   W   = d_in[i]; break;
      case 2048:     a   = d_in[i]; break;
      default: break;
    }
  }
  float* out = (float*)d_out;  // fp32 [4096,256]

  char* ws = (char*)d_ws;
  const size_t OFF_ADJF = 0;                       // 33,554,432  adj as f16
  const size_t OFF_VT   = 33554432;                //  9,437,184  VT [1152 x 4096] f16
  const size_t OFF_TGT  = OFF_VT + 9437184;        //     65,536  tgt fp32 [4 x 4096]
  const size_t OFF_WBUF = OFF_TGT + 65536;         //     65,536  w fp32 [4 x 4096]
  const size_t OFF_M    = OFF_WBUF + 65536;        //        256  per-head max (fp32[4]) + flag
  const size_t OFF_AF   = OFF_M + 256;             //      8,192  a as fp32
  const size_t OFF_X    = OFF_AF + 8192;           // overlap region
  const size_t NEED     = OFF_X + 18874368;        // S fp32 [4096 x 1152]
  if (ws_size < NEED || !h || !adj || !W || !a) return;

  _Float16* adjF = (_Float16*)(ws + OFF_ADJF);
  _Float16* VT   = (_Float16*)(ws + OFF_VT);
  float*    tgt  = (float*)(ws + OFF_TGT);
  float*    wbuf = (float*)(ws + OFF_WBUF);
  float*    mF   = (float*)(ws + OFF_M);
  int*      flag = (int*)(ws + OFF_M + 32);
  float*    aF   = (float*)(ws + OFF_AF);
  // region X: hF/WT/ht live until scaled_transpose; S (the adj-GEMM output) aliases them after
  _Float16* hF = (_Float16*)(ws + OFF_X);                  // 4,194,304
  _Float16* WT = (_Float16*)(ws + OFF_X + 4194304);        // 1,048,576
  _Float16* ht = (_Float16*)(ws + OFF_X + 5242880);        // 8,388,608
  float*    S  = (float*)(ws + OFF_X);                     // 18,874,368 (aliases dead hF/WT/ht)

  detect_kernel<<<1, 256, 0, stream>>>((const unsigned short*)h, flag);
  cvt_h_kernel<<<1024, 256, 0, stream>>>(h, hF, flag, 262144);
  cvt_adj_kernel<<<8192, 256, 0, stream>>>(adj, adjF, 2097152);
  cvt_a_kernel<<<1, 256, 0, stream>>>(a, aF, flag);
  transpose_w_kernel<<<dim3(8, 16), 256, 0, stream>>>(W, WT, flag);
  // ht[4096 x 1024] = h @ W
  gemm_bt<_Float16><<<dim3(8, 32), 256, 0, stream>>>(hF, WT, ht, F_IN, HD);
  tgt_kernel<<<4096, 256, 0, stream>>>(ht, aF, tgt);
  reduce_max_kernel<<<4, 256, 0, stream>>>(tgt, mF);
  wexp_kernel<<<dim3(16, 4), 256, 0, stream>>>(tgt, mF, wbuf, VT);
  scaled_transpose_kernel<<<dim3(64, 16), 256, 0, stream>>>(ht, wbuf, VT);
  // S[4096 x 1152] = adj @ [w*ht | w]
  gemm_bt<float><<<dim3(9, 32), 256, 0, stream>>>(adjF, VT, S, N_NODES, NPAD);
  epilogue_kernel<<<4096, 256, 0, stream>>>(S, out);
}